// Round 6
// baseline (1161.268 us; speedup 1.0000x reference)
//
#include <hip/hip_runtime.h>
#include <math.h>

#define TWO_PI_F 6.283185307179586f
#define PI_4_F   0.7853981633974483f

typedef __attribute__((ext_vector_type(8))) short short8;
typedef __attribute__((ext_vector_type(4))) float f32x4;
typedef __attribute__((ext_vector_type(4))) unsigned short ushort4v;
typedef __attribute__((ext_vector_type(2))) float f2v;

struct Tap { int i00, i01, i10, i11; float w00, w01, w10, w11; };

static __device__ __forceinline__ unsigned short f2bf(float f) {
    unsigned u = __builtin_bit_cast(unsigned, f);
    u = (u + 0x7fffu + ((u >> 16) & 1u)) >> 16;
    return (unsigned short)u;
}

// ---------------------------------------------------------------------------
// Build per-resolution sampling tables. AoS Tap (fp32 conv1_1 path) and the
// PAIR table SoA planes tabP[(kt*6+comp)*HW + p]:
//   comp 0: r0 (top-row pair base), 1: r1 (bottom-row pair base),
//   comp 2,3: ta0,ta1 (top-pair coeffs), 4,5: ba0,ba1 (bottom-pair coeffs).
// Validity folded into coefficients; pair base clamped to [0, S-2] so the
// 8-byte load {v[r], v[r+1]} is always in-bounds. Same products as the
// reference bilinear (reassociated sum only).
// ---------------------------------------------------------------------------
__global__ void build_table_kernel(Tap* __restrict__ tab, int* __restrict__ tabP, int S) {
    int idx = blockIdx.x * blockDim.x + threadIdx.x;
    int total = S * S * 9;
    if (idx >= total) return;
    int k = idx % 9;
    int p = idx / 9;
    int y = p / S;
    int x = p - y * S;
    int HW = S * S;

    float c = 0.5f * (float)S - 0.5f;
    float theta = atan2f((float)x - c, (float)y - c);
    theta = fmodf(theta, TWO_PI_F);
    if (theta < 0.0f) theta += TWO_PI_F;
    theta = rintf(theta * 10000.0f) / 10000.0f;

    float offy = 0.0f, offx = 0.0f;
    if (k != 4) {
        int m = (k < 4) ? k : (k - 1);
        const float ayt[8] = { 1.f, 1.f,  1.f, 0.f,  0.f, -1.f, -1.f, -1.f };
        const float axt[8] = { 1.f, 0.f, -1.f, 1.f, -1.f,  1.f,  0.f, -1.f };
        float ang = theta + PI_4_F * (float)m;
        offy = cosf(ang) + ayt[m];
        offx = sinf(ang) + axt[m];
    }
    int ky = k / 3, kx = k - ky * 3;
    float py = (float)y - 1.0f + (float)ky + offy;
    float px = (float)x - 1.0f + (float)kx + offx;
    float fy0 = floorf(py), fx0 = floorf(px);
    float wy = py - fy0, wx = px - fx0;
    float fmaxc = (float)(S - 1);

    Tap t;
    {
        float yy = fy0, xx = fx0;
        bool v = (yy >= 0.f) && (yy <= fmaxc) && (xx >= 0.f) && (xx <= fmaxc);
        int yi = (int)fminf(fmaxf(yy, 0.f), fmaxc);
        int xi = (int)fminf(fmaxf(xx, 0.f), fmaxc);
        t.i00 = yi * S + xi;
        t.w00 = v ? (1.f - wy) * (1.f - wx) : 0.f;
    }
    {
        float yy = fy0, xx = fx0 + 1.0f;
        bool v = (yy >= 0.f) && (yy <= fmaxc) && (xx >= 0.f) && (xx <= fmaxc);
        int yi = (int)fminf(fmaxf(yy, 0.f), fmaxc);
        int xi = (int)fminf(fmaxf(xx, 0.f), fmaxc);
        t.i01 = yi * S + xi;
        t.w01 = v ? (1.f - wy) * wx : 0.f;
    }
    {
        float yy = fy0 + 1.0f, xx = fx0;
        bool v = (yy >= 0.f) && (yy <= fmaxc) && (xx >= 0.f) && (xx <= fmaxc);
        int yi = (int)fminf(fmaxf(yy, 0.f), fmaxc);
        int xi = (int)fminf(fmaxf(xx, 0.f), fmaxc);
        t.i10 = yi * S + xi;
        t.w10 = v ? wy * (1.f - wx) : 0.f;
    }
    {
        float yy = fy0 + 1.0f, xx = fx0 + 1.0f;
        bool v = (yy >= 0.f) && (yy <= fmaxc) && (xx >= 0.f) && (xx <= fmaxc);
        int yi = (int)fminf(fmaxf(yy, 0.f), fmaxc);
        int xi = (int)fminf(fmaxf(xx, 0.f), fmaxc);
        t.i11 = yi * S + xi;
        t.w11 = v ? wy * wx : 0.f;
    }
    tab[idx] = t;

    bool vy0 = (fy0 >= 0.f) && (fy0 <= fmaxc);
    bool vy1 = (fy0 + 1.f >= 0.f) && (fy0 + 1.f <= fmaxc);
    bool vx0 = (fx0 >= 0.f) && (fx0 <= fmaxc);
    bool vx1 = (fx0 + 1.f >= 0.f) && (fx0 + 1.f <= fmaxc);
    int y0c = (int)fminf(fmaxf(fy0, 0.f), fmaxc);
    int y1c = (int)fminf(fmaxf(fy0 + 1.f, 0.f), fmaxc);
    int xb  = (int)fminf(fmaxf(fx0, 0.f), (float)(S - 2));
    int off0 = (int)fminf(fmaxf(fx0, 0.f), fmaxc) - xb;
    int off1 = (int)fminf(fmaxf(fx0 + 1.f, 0.f), fmaxc) - xb;
    float a0 = 0.f, a1 = 0.f;
    if (vx0) { if (off0) a1 += (1.f - wx); else a0 += (1.f - wx); }
    if (vx1) { if (off1) a1 += wx;         else a0 += wx; }
    float ta0 = vy0 ? (1.f - wy) * a0 : 0.f;
    float ta1 = vy0 ? (1.f - wy) * a1 : 0.f;
    float ba0 = vy1 ? wy * a0 : 0.f;
    float ba1 = vy1 ? wy * a1 : 0.f;

    tabP[(k * 6 + 0) * HW + p] = y0c * S + xb;
    tabP[(k * 6 + 1) * HW + p] = y1c * S + xb;
    tabP[(k * 6 + 2) * HW + p] = __builtin_bit_cast(int, ta0);
    tabP[(k * 6 + 3) * HW + p] = __builtin_bit_cast(int, ta1);
    tabP[(k * 6 + 4) * HW + p] = __builtin_bit_cast(int, ba0);
    tabP[(k * 6 + 5) * HW + p] = __builtin_bit_cast(int, ba1);
}

// ---------------------------------------------------------------------------
// Pack fp32 weights w[O][C][9] -> bf16 fragment order wP[kb][o][32],
// TAP-MAJOR K: K = kt*C + c. Requires C % 32 == 0.
// ---------------------------------------------------------------------------
__global__ void pack_w_kernel(const float* __restrict__ w, unsigned short* __restrict__ wP,
                              int O, int C, int total) {
    int idx = blockIdx.x * blockDim.x + threadIdx.x;
    if (idx >= total) return;
    int ksub = idx & 31;
    int kbo  = idx >> 5;
    int o  = kbo % O;
    int kb = kbo / O;
    int K = kb * 32 + ksub;
    int kt = K / C;
    int c  = K - kt * C;
    wP[idx] = f2bf(w[((size_t)o * C + c) * 9 + kt]);
}

// ---------------------------------------------------------------------------
// fp32 conv for conv1_1 only (C=3, 0.3% of FLOPs).
// ---------------------------------------------------------------------------
__global__ __launch_bounds__(256) void dconv_f32_kernel(
    const float* __restrict__ x, const float* __restrict__ w,
    const Tap* __restrict__ tab, float* __restrict__ out,
    int C, int O, int HW)
{
    __shared__ float4 sTabRaw[64 * 9 * 2];
    __shared__ float  sS[9][64];
    __shared__ float  sW[9][64];

    const int tid = threadIdx.x;
    const int b  = blockIdx.z;
    const int o0 = blockIdx.y * 64;
    const int p0 = blockIdx.x * 64;
    const int C9 = C * 9;

    const float4* gt = (const float4*)(tab + (size_t)p0 * 9);
    for (int i = tid; i < 64 * 9 * 2; i += 256) sTabRaw[i] = gt[i];
    const Tap* sTab = (const Tap*)sTabRaw;
    __syncthreads();

    float acc[4][4];
#pragma unroll
    for (int i = 0; i < 4; ++i)
#pragma unroll
        for (int j = 0; j < 4; ++j) acc[i][j] = 0.f;

    const int to = tid >> 4;
    const int tn = tid & 15;
    const float* xb = x + (size_t)b * C * HW;

    for (int c = 0; c < C; ++c) {
        const float* xp = xb + (size_t)c * HW;
        for (int i = tid; i < 9 * 64; i += 256) {
            int k = i >> 6;
            int p = i & 63;
            Tap t = sTab[p * 9 + k];
            sS[k][p] = t.w00 * xp[t.i00] + t.w01 * xp[t.i01]
                     + t.w10 * xp[t.i10] + t.w11 * xp[t.i11];
        }
        for (int i = tid; i < 9 * 64; i += 256) {
            int k = i >> 6;
            int o = i & 63;
            sW[k][o] = w[(size_t)(o0 + o) * C9 + c * 9 + k];
        }
        __syncthreads();
#pragma unroll
        for (int k = 0; k < 9; ++k) {
            float4 wv = *(const float4*)&sW[k][to * 4];
            float4 sv = *(const float4*)&sS[k][tn * 4];
            acc[0][0] += wv.x * sv.x; acc[0][1] += wv.x * sv.y; acc[0][2] += wv.x * sv.z; acc[0][3] += wv.x * sv.w;
            acc[1][0] += wv.y * sv.x; acc[1][1] += wv.y * sv.y; acc[1][2] += wv.y * sv.z; acc[1][3] += wv.y * sv.w;
            acc[2][0] += wv.z * sv.x; acc[2][1] += wv.z * sv.y; acc[2][2] += wv.z * sv.z; acc[2][3] += wv.z * sv.w;
            acc[3][0] += wv.w * sv.x; acc[3][1] += wv.w * sv.y; acc[3][2] += wv.w * sv.z; acc[3][3] += wv.w * sv.w;
        }
        __syncthreads();
    }

#pragma unroll
    for (int i = 0; i < 4; ++i) {
        int o = o0 + to * 4 + i;
        float* op = out + ((size_t)b * O + o) * HW + p0 + tn * 4;
        float4 v;
        v.x = fmaxf(acc[i][0], 0.f);
        v.y = fmaxf(acc[i][1], 0.f);
        v.z = fmaxf(acc[i][2], 0.f);
        v.w = fmaxf(acc[i][3], 0.f);
        *(float4*)op = v;
    }
}

// ---------------------------------------------------------------------------
// MFMA deform-conv, pair-gather sampler (lane = pixel, 2x8B loads/sample).
// Round-4 tiling: BM out-channels x 64 pixels, no OT, no swizzle.
// ---------------------------------------------------------------------------
#define SPITCH 296   // ushorts per px row (288 + 8 pad; row = 592B, 16B aligned)

template<int BM>
__global__ __launch_bounds__(256, 4) void dconv_mfma(
    const float* __restrict__ x, const unsigned short* __restrict__ wP,
    const int* __restrict__ tabP, float* __restrict__ out,
    float* __restrict__ part,
    int C, int O, int HW, int Cchunk, int nChunks)
{
    __shared__ unsigned short sS[64 * SPITCH];    // 37888 B

    const int tid  = threadIdx.x;
    const int lane = tid & 63;
    const int wv   = tid >> 6;
    const int bz = blockIdx.z;
    const int b     = bz & 7;
    const int chunk = bz >> 3;
    const int o0 = blockIdx.y * BM;
    const int p0 = blockIdx.x * 64;
    const int c0 = chunk * Cchunk;
    const int nGroups = Cchunk >> 5;

    const int o0w = (BM == 128) ? wv * 32 : (wv >> 1) * 32;
    const int p0w = (BM == 128) ? 0       : (wv & 1) * 32;
    constexpr int MF = 2;
    constexpr int NF = (BM == 128) ? 4 : 2;

    f32x4 acc[MF][NF] = {};

    const float* xb = x + (size_t)b * C * HW;
    const int quad = lane >> 4;
    const int l16  = lane & 15;
    const int* tp0 = tabP + p0 + lane;   // lane's pixel column in SoA planes

    for (int g = 0; g < nGroups; ++g) {
        const int cg = c0 + g * 32;
        const float* xw = xb + (size_t)(cg + wv * 8) * HW;
        unsigned short* srow = &sS[lane * SPITCH + wv * 8];

        // ---- sample: 9 taps x 8 channels, lane = pixel, 2 pair-loads/sample
        for (int kt = 0; kt < 9; ++kt) {
            const int* tp = tp0 + kt * 6 * HW;
            int   r0  = tp[0];
            int   r1  = tp[HW];
            float ta0 = __builtin_bit_cast(float, tp[2 * HW]);
            float ta1 = __builtin_bit_cast(float, tp[3 * HW]);
            float ba0 = __builtin_bit_cast(float, tp[4 * HW]);
            float ba1 = __builtin_bit_cast(float, tp[5 * HW]);
#pragma unroll
            for (int cq = 0; cq < 2; ++cq) {
                float v[4];
#pragma unroll
                for (int j = 0; j < 4; ++j) {
                    const float* xc = xw + (size_t)(cq * 4 + j) * HW;
                    f2v pt, pb;
                    __builtin_memcpy(&pt, xc + r0, 8);
                    __builtin_memcpy(&pb, xc + r1, 8);
                    v[j] = ta0 * pt.x + ta1 * pt.y + ba0 * pb.x + ba1 * pb.y;
                }
                ushort4v pk;
                pk.x = f2bf(v[0]); pk.y = f2bf(v[1]);
                pk.z = f2bf(v[2]); pk.w = f2bf(v[3]);
                *(ushort4v*)(srow + kt * 32 + cq * 4) = pk;
            }
        }
        __syncthreads();

        // ---- 9 MFMA k-steps; K-tile for tap kt is kb = (kt*C + cg)/32
#pragma unroll 3
        for (int kt = 0; kt < 9; ++kt) {
            const int kb = (kt * C + cg) >> 5;
            short8 afr[MF], bfr[NF];
#pragma unroll
            for (int mf = 0; mf < MF; ++mf) {
                int orow = o0 + o0w + mf * 16 + l16;
                afr[mf] = *(const short8*)(wP + (((size_t)kb * O + orow) << 5) + (quad << 3));
            }
#pragma unroll
            for (int nf = 0; nf < NF; ++nf) {
                int prow = p0w + nf * 16 + l16;
                bfr[nf] = *(const short8*)(&sS[prow * SPITCH + kt * 32 + (quad << 3)]);
            }
#pragma unroll
            for (int mf = 0; mf < MF; ++mf)
#pragma unroll
                for (int nf = 0; nf < NF; ++nf)
                    acc[mf][nf] = __builtin_amdgcn_mfma_f32_16x16x32_bf16(afr[mf], bfr[nf], acc[mf][nf], 0, 0, 0);
        }
        __syncthreads();
    }

    if (nChunks == 1) {
#pragma unroll
        for (int mf = 0; mf < MF; ++mf)
#pragma unroll
            for (int nf = 0; nf < NF; ++nf)
#pragma unroll
                for (int r = 0; r < 4; ++r) {
                    int o = o0 + o0w + mf * 16 + (quad << 2) + r;
                    int p = p0 + p0w + nf * 16 + l16;
                    out[((size_t)b * O + o) * HW + p] = fmaxf(acc[mf][nf][r], 0.f);
                }
    } else {
        float* pb = part + (size_t)chunk * 8 * O * HW;
#pragma unroll
        for (int mf = 0; mf < MF; ++mf)
#pragma unroll
            for (int nf = 0; nf < NF; ++nf)
#pragma unroll
                for (int r = 0; r < 4; ++r) {
                    int o = o0 + o0w + mf * 16 + (quad << 2) + r;
                    int p = p0 + p0w + nf * 16 + l16;
                    pb[((size_t)b * O + o) * HW + p] = acc[mf][nf][r];
                }
    }
}

// sum partial chunks + ReLU (float4)
__global__ void reduce_relu_kernel(const float* __restrict__ part,
                                   float* __restrict__ out,
                                   int per4, int nChunks)
{
    int idx = blockIdx.x * blockDim.x + threadIdx.x;
    if (idx >= per4) return;
    const float4* p4 = (const float4*)part;
    float4 s = p4[idx];
    for (int ch = 1; ch < nChunks; ++ch) {
        float4 v = p4[(size_t)ch * per4 + idx];
        s.x += v.x; s.y += v.y; s.z += v.z; s.w += v.w;
    }
    float4 r;
    r.x = fmaxf(s.x, 0.f); r.y = fmaxf(s.y, 0.f);
    r.z = fmaxf(s.z, 0.f); r.w = fmaxf(s.w, 0.f);
    ((float4*)out)[idx] = r;
}

// sum partial chunks + ReLU + 2x2 maxpool (relu(max) == max(sums, 0))
__global__ void reduce_relu_pool_kernel(const float* __restrict__ part,
                                        float* __restrict__ out,
                                        int H, int per, int nChunks, int total)
{
    int idx = blockIdx.x * blockDim.x + threadIdx.x;
    if (idx >= total) return;
    int H2 = H >> 1;
    int x2 = idx % H2;
    int t  = idx / H2;
    int y2 = t % H2;
    t /= H2;                       // t = b*C + c
    int base = (t * H + 2 * y2) * H + 2 * x2;
    float s0 = 0.f, s1 = 0.f, s2 = 0.f, s3 = 0.f;
    for (int ch = 0; ch < nChunks; ++ch) {
        const float* p = part + (size_t)ch * per + base;
        s0 += p[0]; s1 += p[1]; s2 += p[H]; s3 += p[H + 1];
    }
    out[idx] = fmaxf(fmaxf(fmaxf(s0, s1), fmaxf(s2, s3)), 0.f);
}

__global__ void maxpool_kernel(const float* __restrict__ in, float* __restrict__ out,
                               int H, int W, int total)
{
    int idx = blockIdx.x * blockDim.x + threadIdx.x;
    if (idx >= total) return;
    int W2 = W >> 1, H2 = H >> 1;
    int x2 = idx % W2;
    int t  = idx / W2;
    int y2 = t % H2;
    t /= H2;
    const float* p = in + ((size_t)t * H + 2 * y2) * W + 2 * x2;
    out[idx] = fmaxf(fmaxf(p[0], p[1]), fmaxf(p[W], p[W + 1]));
}

__global__ void avgpool_kernel(const float* __restrict__ in, float* __restrict__ out, int total)
{
    int idx = blockIdx.x * blockDim.x + threadIdx.x;
    if (idx >= total) return;
    const float* p = in + (size_t)idx * 16;
    float s = 0.f;
#pragma unroll
    for (int i = 0; i < 16; ++i) s += p[i];
    out[idx] = s * (1.0f / 16.0f);
}

__global__ __launch_bounds__(256) void fc_kernel(
    const float* __restrict__ x, const float* __restrict__ w,
    const float* __restrict__ bias, float* __restrict__ out,
    int K, int O, int relu)
{
    int o = blockIdx.x;
    float acc[8] = {0.f,0.f,0.f,0.f,0.f,0.f,0.f,0.f};
    const float* wr = w + (size_t)o * K;
    for (int k = threadIdx.x; k < K; k += 256) {
        float wv = wr[k];
#pragma unroll
        for (int b = 0; b < 8; ++b) acc[b] += wv * x[(size_t)b * K + k];
    }
    __shared__ float red[8][256];
#pragma unroll
    for (int b = 0; b < 8; ++b) red[b][threadIdx.x] = acc[b];
    __syncthreads();
    for (int s = 128; s > 0; s >>= 1) {
        if (threadIdx.x < s) {
#pragma unroll
            for (int b = 0; b < 8; ++b) red[b][threadIdx.x] += red[b][threadIdx.x + s];
        }
        __syncthreads();
    }
    if (threadIdx.x < 8) {
        float v = red[threadIdx.x][0] + bias[o];
        if (relu) v = fmaxf(v, 0.f);
        out[(size_t)threadIdx.x * O + o] = v;
    }
}

// ---------------------------------------------------------------------------
// Host orchestration (round-4 chunking: nCh = 1/2/2/4/16, no OT, no swizzle)
// ---------------------------------------------------------------------------
extern "C" void kernel_launch(void* const* d_in, const int* in_sizes, int n_in,
                              void* d_out, int out_size, void* d_ws, size_t ws_size,
                              hipStream_t stream) {
    const float* x    = (const float*)d_in[0];
    const float* wf[13];
    for (int i = 0; i < 13; ++i) wf[i] = (const float*)d_in[1 + i];
    const float* fc1w = (const float*)d_in[14];
    const float* fc1b = (const float*)d_in[15];
    const float* fc2w = (const float*)d_in[16];
    const float* fc2b = (const float*)d_in[17];
    const float* fc3w = (const float*)d_in[18];
    const float* fc3b = (const float*)d_in[19];
    float* out = (float*)d_out;

    char* ws = (char*)d_ws;
    auto alloc = [&](size_t bytes) -> char* {
        char* p = ws;
        ws += (bytes + 255) & ~(size_t)255;
        return p;
    };

    const int sizes[5] = {128, 64, 32, 16, 8};
    Tap* tabs[5];
    int* tabPs[5];
    for (int i = 0; i < 5; ++i) {
        int HW = sizes[i] * sizes[i];
        tabs[i]  = (Tap*)alloc((size_t)HW * 9 * sizeof(Tap));
        tabPs[i] = (int*)alloc((size_t)HW * 9 * 6 * sizeof(int));
    }
    float* actA = (float*)alloc((size_t)8 * 64 * 128 * 128 * sizeof(float));
    float* actB = (float*)alloc((size_t)8 * 64 * 128 * 128 * sizeof(float));
    float* partial = (float*)alloc((size_t)2 * 8 * 128 * 4096 * sizeof(float)); // 33.6 MB max
    const int Cs[13] = {3, 64, 64, 128, 128, 256, 256, 256, 512, 512, 512, 512, 512};
    const int Os[13] = {64, 64, 128, 128, 256, 256, 256, 512, 512, 512, 512, 512, 512};
    unsigned short* wPk[13];
    wPk[0] = nullptr;
    for (int i = 1; i < 13; ++i)
        wPk[i] = (unsigned short*)alloc((size_t)Os[i] * Cs[i] * 9 * sizeof(unsigned short));
    float* pooled = (float*)alloc((size_t)8 * 512 * sizeof(float));
    float* fcb1 = (float*)alloc((size_t)8 * 4096 * sizeof(float));
    float* fcb2 = (float*)alloc((size_t)8 * 4096 * sizeof(float));

    for (int i = 0; i < 5; ++i) {
        int total = sizes[i] * sizes[i] * 9;
        build_table_kernel<<<(total + 255) / 256, 256, 0, stream>>>(tabs[i], tabPs[i], sizes[i]);
    }
    for (int i = 1; i < 13; ++i) {
        int total = Os[i] * Cs[i] * 9;
        pack_w_kernel<<<(total + 255) / 256, 256, 0, stream>>>(wf[i], wPk[i], Os[i], Cs[i], total);
    }

    auto convM = [&](const float* in, const unsigned short* wp, int* tabP, float* o,
                     int C, int O, int S, int nCh, bool leavePartial) {
        int HW = S * S;
        int Cchunk = C / nCh;
        if (O == 64) {
            dim3 grid(HW / 64, 1, 8 * nCh);
            dconv_mfma<64><<<grid, 256, 0, stream>>>(in, wp, tabP, o, partial, C, O, HW, Cchunk, nCh);
        } else {
            dim3 grid(HW / 64, O / 128, 8 * nCh);
            dconv_mfma<128><<<grid, 256, 0, stream>>>(in, wp, tabP, o, partial, C, O, HW, Cchunk, nCh);
        }
        if (nCh > 1 && !leavePartial) {
            int per4 = 8 * O * HW / 4;
            reduce_relu_kernel<<<(per4 + 255) / 256, 256, 0, stream>>>(partial, o, per4, nCh);
        }
    };
    auto fusedPool = [&](float* o, int C, int H, int nCh) {
        int per = 8 * C * H * H;
        int total = per / 4;
        reduce_relu_pool_kernel<<<(total + 255) / 256, 256, 0, stream>>>(partial, o, H, per, nCh, total);
    };

    // conv1_1: fp32 path (C=3)
    {
        dim3 grid(128 * 128 / 64, 1, 8);
        dconv_f32_kernel<<<grid, 256, 0, stream>>>(x, wf[0], tabs[0], actA, 3, 64, 128 * 128);
    }
    convM(actA, wPk[1],  tabPs[0], actB, 64,  64,  128, 1, false);   // conv1_2 -> actB
    {
        int total = 8 * 64 * 64 * 64;
        maxpool_kernel<<<(total + 255) / 256, 256, 0, stream>>>(actB, actA, 128, 128, total);
    }
    convM(actA, wPk[2],  tabPs[1], actB, 64,  128, 64, 2, false);    // conv2_1 -> actB
    convM(actB, wPk[3],  tabPs[1], nullptr, 128, 128, 64, 2, true);  // conv2_2 -> partial
    fusedPool(actA, 128, 64, 2);                                     // -> actA (128ch @32^2)
    convM(actA, wPk[4],  tabPs[2], actB, 128, 256, 32, 2, false);    // conv3_1 -> actB
    convM(actB, wPk[5],  tabPs[2], actA, 256, 256, 32, 2, false);    // conv3_2 -> actA
    convM(actA, wPk[6],  tabPs[2], nullptr, 256, 256, 32, 2, true);  // conv3_3 -> partial
    fusedPool(actB, 256, 32, 2);                                     // -> actB (256ch @16^2)
    convM(actB, wPk[7],  tabPs[3], actA, 256, 512, 16, 4, false);    // conv4_1 -> actA
    convM(actA, wPk[8],  tabPs[3], actB, 512, 512, 16, 4, false);    // conv4_2 -> actB
    convM(actB, wPk[9],  tabPs[3], nullptr, 512, 512, 16, 4, true);  // conv4_3 -> partial
    fusedPool(actA, 512, 16, 4);                                     // -> actA (512ch @8^2)
    convM(actA, wPk[10], tabPs[4], actB, 512, 512, 8, 16, false);    // conv5_1 -> actB
    convM(actB, wPk[11], tabPs[4], actA, 512, 512, 8, 16, false);    // conv5_2 -> actA
    convM(actA, wPk[12], tabPs[4], nullptr, 512, 512, 8, 16, true);  // conv5_3 -> partial
    fusedPool(actB, 512, 8, 16);                                     // -> actB (512ch @4^2)

    avgpool_kernel<<<(4096 + 255) / 256, 256, 0, stream>>>(actB, pooled, 8 * 512);

    fc_kernel<<<4096, 256, 0, stream>>>(pooled, fc1w, fc1b, fcb1, 512,  4096, 1);
    fc_kernel<<<4096, 256, 0, stream>>>(fcb1,   fc2w, fc2b, fcb2, 4096, 4096, 1);
    fc_kernel<<<30,   256, 0, stream>>>(fcb2,   fc3w, fc3b, out,  4096, 30,   0);
}

// Round 7
// 900.774 us; speedup vs baseline: 1.2892x; 1.2892x over previous
//
#include <hip/hip_runtime.h>
#include <math.h>

#define TWO_PI_F 6.283185307179586f
#define PI_4_F   0.7853981633974483f

typedef __attribute__((ext_vector_type(8))) short short8;
typedef __attribute__((ext_vector_type(4))) float f32x4;
typedef __attribute__((ext_vector_type(4))) unsigned short ushort4v;

struct Tap { int i00, i01, i10, i11; float w00, w01, w10, w11; };

static __device__ __forceinline__ unsigned short f2bf(float f) {
    unsigned u = __builtin_bit_cast(unsigned, f);
    u = (u + 0x7fffu + ((u >> 16) & 1u)) >> 16;
    return (unsigned short)u;
}
static __device__ __forceinline__ float bf2f(unsigned short u) {
    return __builtin_bit_cast(float, (unsigned)u << 16);
}

// ---------------------------------------------------------------------------
// Build per-resolution sampling tables. AoS Tap (fp32 conv1_1 path) and SoA
// planes tabT[(kt*8+comp)*HW + p] (comp 0-3: indices, 4-7: weight bits).
// Exact replication of reference coordinate math (round-1 absmax 0.0).
// ---------------------------------------------------------------------------
__global__ void build_table_kernel(Tap* __restrict__ tab, int* __restrict__ tabT, int S) {
    int idx = blockIdx.x * blockDim.x + threadIdx.x;
    int total = S * S * 9;
    if (idx >= total) return;
    int k = idx % 9;
    int p = idx / 9;
    int y = p / S;
    int x = p - y * S;
    int HW = S * S;

    float c = 0.5f * (float)S - 0.5f;
    float theta = atan2f((float)x - c, (float)y - c);
    theta = fmodf(theta, TWO_PI_F);
    if (theta < 0.0f) theta += TWO_PI_F;
    theta = rintf(theta * 10000.0f) / 10000.0f;

    float offy = 0.0f, offx = 0.0f;
    if (k != 4) {
        int m = (k < 4) ? k : (k - 1);
        const float ayt[8] = { 1.f, 1.f,  1.f, 0.f,  0.f, -1.f, -1.f, -1.f };
        const float axt[8] = { 1.f, 0.f, -1.f, 1.f, -1.f,  1.f,  0.f, -1.f };
        float ang = theta + PI_4_F * (float)m;
        offy = cosf(ang) + ayt[m];
        offx = sinf(ang) + axt[m];
    }
    int ky = k / 3, kx = k - ky * 3;
    float py = (float)y - 1.0f + (float)ky + offy;
    float px = (float)x - 1.0f + (float)kx + offx;
    float fy0 = floorf(py), fx0 = floorf(px);
    float wy = py - fy0, wx = px - fx0;
    float fmaxc = (float)(S - 1);

    Tap t;
    {
        float yy = fy0, xx = fx0;
        bool v = (yy >= 0.f) && (yy <= fmaxc) && (xx >= 0.f) && (xx <= fmaxc);
        int yi = (int)fminf(fmaxf(yy, 0.f), fmaxc);
        int xi = (int)fminf(fmaxf(xx, 0.f), fmaxc);
        t.i00 = yi * S + xi;
        t.w00 = v ? (1.f - wy) * (1.f - wx) : 0.f;
    }
    {
        float yy = fy0, xx = fx0 + 1.0f;
        bool v = (yy >= 0.f) && (yy <= fmaxc) && (xx >= 0.f) && (xx <= fmaxc);
        int yi = (int)fminf(fmaxf(yy, 0.f), fmaxc);
        int xi = (int)fminf(fmaxf(xx, 0.f), fmaxc);
        t.i01 = yi * S + xi;
        t.w01 = v ? (1.f - wy) * wx : 0.f;
    }
    {
        float yy = fy0 + 1.0f, xx = fx0;
        bool v = (yy >= 0.f) && (yy <= fmaxc) && (xx >= 0.f) && (xx <= fmaxc);
        int yi = (int)fminf(fmaxf(yy, 0.f), fmaxc);
        int xi = (int)fminf(fmaxf(xx, 0.f), fmaxc);
        t.i10 = yi * S + xi;
        t.w10 = v ? wy * (1.f - wx) : 0.f;
    }
    {
        float yy = fy0 + 1.0f, xx = fx0 + 1.0f;
        bool v = (yy >= 0.f) && (yy <= fmaxc) && (xx >= 0.f) && (xx <= fmaxc);
        int yi = (int)fminf(fmaxf(yy, 0.f), fmaxc);
        int xi = (int)fminf(fmaxf(xx, 0.f), fmaxc);
        t.i11 = yi * S + xi;
        t.w11 = v ? wy * wx : 0.f;
    }
    tab[idx] = t;

    tabT[(k * 8 + 0) * HW + p] = t.i00;
    tabT[(k * 8 + 1) * HW + p] = t.i01;
    tabT[(k * 8 + 2) * HW + p] = t.i10;
    tabT[(k * 8 + 3) * HW + p] = t.i11;
    tabT[(k * 8 + 4) * HW + p] = __builtin_bit_cast(int, t.w00);
    tabT[(k * 8 + 5) * HW + p] = __builtin_bit_cast(int, t.w01);
    tabT[(k * 8 + 6) * HW + p] = __builtin_bit_cast(int, t.w10);
    tabT[(k * 8 + 7) * HW + p] = __builtin_bit_cast(int, t.w11);
}

// ---------------------------------------------------------------------------
// Pack fp32 weights w[O][C][9] -> bf16 fragment order wP[kb][o][32],
// TAP-MAJOR K: K = kt*C + c. Requires C % 32 == 0.
// ---------------------------------------------------------------------------
__global__ void pack_w_kernel(const float* __restrict__ w, unsigned short* __restrict__ wP,
                              int O, int C, int total) {
    int idx = blockIdx.x * blockDim.x + threadIdx.x;
    if (idx >= total) return;
    int ksub = idx & 31;
    int kbo  = idx >> 5;
    int o  = kbo % O;
    int kb = kbo / O;
    int K = kb * 32 + ksub;
    int kt = K / C;
    int c  = K - kt * C;
    wP[idx] = f2bf(w[((size_t)o * C + c) * 9 + kt]);
}

// ---------------------------------------------------------------------------
// fp32 conv for conv1_1 only (C=3, fp32 input); output bf16.
// ---------------------------------------------------------------------------
__global__ __launch_bounds__(256) void dconv_f32_kernel(
    const float* __restrict__ x, const float* __restrict__ w,
    const Tap* __restrict__ tab, unsigned short* __restrict__ out,
    int C, int O, int HW)
{
    __shared__ float4 sTabRaw[64 * 9 * 2];
    __shared__ float  sS[9][64];
    __shared__ float  sW[9][64];

    const int tid = threadIdx.x;
    const int b  = blockIdx.z;
    const int o0 = blockIdx.y * 64;
    const int p0 = blockIdx.x * 64;
    const int C9 = C * 9;

    const float4* gt = (const float4*)(tab + (size_t)p0 * 9);
    for (int i = tid; i < 64 * 9 * 2; i += 256) sTabRaw[i] = gt[i];
    const Tap* sTab = (const Tap*)sTabRaw;
    __syncthreads();

    float acc[4][4];
#pragma unroll
    for (int i = 0; i < 4; ++i)
#pragma unroll
        for (int j = 0; j < 4; ++j) acc[i][j] = 0.f;

    const int to = tid >> 4;
    const int tn = tid & 15;
    const float* xb = x + (size_t)b * C * HW;

    for (int c = 0; c < C; ++c) {
        const float* xp = xb + (size_t)c * HW;
        for (int i = tid; i < 9 * 64; i += 256) {
            int k = i >> 6;
            int p = i & 63;
            Tap t = sTab[p * 9 + k];
            sS[k][p] = t.w00 * xp[t.i00] + t.w01 * xp[t.i01]
                     + t.w10 * xp[t.i10] + t.w11 * xp[t.i11];
        }
        for (int i = tid; i < 9 * 64; i += 256) {
            int k = i >> 6;
            int o = i & 63;
            sW[k][o] = w[(size_t)(o0 + o) * C9 + c * 9 + k];
        }
        __syncthreads();
#pragma unroll
        for (int k = 0; k < 9; ++k) {
            float4 wv = *(const float4*)&sW[k][to * 4];
            float4 sv = *(const float4*)&sS[k][tn * 4];
            acc[0][0] += wv.x * sv.x; acc[0][1] += wv.x * sv.y; acc[0][2] += wv.x * sv.z; acc[0][3] += wv.x * sv.w;
            acc[1][0] += wv.y * sv.x; acc[1][1] += wv.y * sv.y; acc[1][2] += wv.y * sv.z; acc[1][3] += wv.y * sv.w;
            acc[2][0] += wv.z * sv.x; acc[2][1] += wv.z * sv.y; acc[2][2] += wv.z * sv.z; acc[2][3] += wv.z * sv.w;
            acc[3][0] += wv.w * sv.x; acc[3][1] += wv.w * sv.y; acc[3][2] += wv.w * sv.z; acc[3][3] += wv.w * sv.w;
        }
        __syncthreads();
    }

#pragma unroll
    for (int i = 0; i < 4; ++i) {
        int o = o0 + to * 4 + i;
        unsigned short* op = out + ((size_t)b * O + o) * HW + p0 + tn * 4;
        ushort4v v;
        v.x = f2bf(fmaxf(acc[i][0], 0.f));
        v.y = f2bf(fmaxf(acc[i][1], 0.f));
        v.z = f2bf(fmaxf(acc[i][2], 0.f));
        v.w = f2bf(fmaxf(acc[i][3], 0.f));
        *(ushort4v*)op = v;
    }
}

// ---------------------------------------------------------------------------
// MFMA deform-conv. Round-4 sampler (lane = pixel, 4x2B gathers from bf16
// activations) + XCD swizzle on pixel tiles. BM out-ch x 64 px, K-split.
// ---------------------------------------------------------------------------
#define SPITCH 296   // ushorts per px row (288 + 8 pad; row = 592B, 16B aligned)

template<int BM>
__global__ __launch_bounds__(256, 4) void dconv_mfma(
    const unsigned short* __restrict__ x, const unsigned short* __restrict__ wP,
    const int* __restrict__ tabT, unsigned short* __restrict__ out,
    float* __restrict__ part,
    int C, int O, int HW, int Cchunk, int nChunks)
{
    __shared__ unsigned short sS[64 * SPITCH];    // 37888 B

    const int tid  = threadIdx.x;
    const int lane = tid & 63;
    const int wv   = tid >> 6;
    const int bz = blockIdx.z;
    const int b     = bz & 7;
    const int chunk = bz >> 3;

    // XCD swizzle: contiguous pixel-tile range per XCD (L2 locality for gathers)
    int bx = blockIdx.x;
    const int gx = gridDim.x;
    if ((gx & 7) == 0) { int g8 = gx >> 3; bx = (bx & 7) * g8 + (bx >> 3); }

    const int o0 = blockIdx.y * BM;
    const int p0 = bx * 64;
    const int c0 = chunk * Cchunk;
    const int nGroups = Cchunk >> 5;

    const int o0w = (BM == 128) ? wv * 32 : (wv >> 1) * 32;
    const int p0w = (BM == 128) ? 0       : (wv & 1) * 32;
    constexpr int MF = 2;
    constexpr int NF = (BM == 128) ? 4 : 2;

    f32x4 acc[MF][NF] = {};

    const unsigned short* xb = x + (size_t)b * C * HW;
    const int quad = lane >> 4;
    const int l16  = lane & 15;
    const int* tp0 = tabT + p0 + lane;   // lane's pixel column in SoA planes

    for (int g = 0; g < nGroups; ++g) {
        const int cg = c0 + g * 32;
        const unsigned short* xw = xb + (size_t)(cg + wv * 8) * HW;
        unsigned short* srow = &sS[lane * SPITCH + wv * 8];

        // ---- sample: 9 taps x 8 channels, lane = pixel (coalesced 2B gathers)
        for (int kt = 0; kt < 9; ++kt) {
            const int* tp = tp0 + kt * 8 * HW;
            int   i00 = tp[0];
            int   i01 = tp[HW];
            int   i10 = tp[2 * HW];
            int   i11 = tp[3 * HW];
            float w00 = __builtin_bit_cast(float, tp[4 * HW]);
            float w01 = __builtin_bit_cast(float, tp[5 * HW]);
            float w10 = __builtin_bit_cast(float, tp[6 * HW]);
            float w11 = __builtin_bit_cast(float, tp[7 * HW]);
#pragma unroll
            for (int cq = 0; cq < 2; ++cq) {
                float v[4];
#pragma unroll
                for (int j = 0; j < 4; ++j) {
                    const unsigned short* xc = xw + (size_t)(cq * 4 + j) * HW;
                    v[j] = w00 * bf2f(xc[i00]) + w01 * bf2f(xc[i01])
                         + w10 * bf2f(xc[i10]) + w11 * bf2f(xc[i11]);
                }
                ushort4v pk;
                pk.x = f2bf(v[0]); pk.y = f2bf(v[1]);
                pk.z = f2bf(v[2]); pk.w = f2bf(v[3]);
                *(ushort4v*)(srow + kt * 32 + cq * 4) = pk;
            }
        }
        __syncthreads();

        // ---- 9 MFMA k-steps; K-tile for tap kt is kb = (kt*C + cg)/32
#pragma unroll 3
        for (int kt = 0; kt < 9; ++kt) {
            const int kb = (kt * C + cg) >> 5;
            short8 afr[MF], bfr[NF];
#pragma unroll
            for (int mf = 0; mf < MF; ++mf) {
                int orow = o0 + o0w + mf * 16 + l16;
                afr[mf] = *(const short8*)(wP + (((size_t)kb * O + orow) << 5) + (quad << 3));
            }
#pragma unroll
            for (int nf = 0; nf < NF; ++nf) {
                int prow = p0w + nf * 16 + l16;
                bfr[nf] = *(const short8*)(&sS[prow * SPITCH + kt * 32 + (quad << 3)]);
            }
#pragma unroll
            for (int mf = 0; mf < MF; ++mf)
#pragma unroll
                for (int nf = 0; nf < NF; ++nf)
                    acc[mf][nf] = __builtin_amdgcn_mfma_f32_16x16x32_bf16(afr[mf], bfr[nf], acc[mf][nf], 0, 0, 0);
        }
        __syncthreads();
    }

    if (nChunks == 1) {
#pragma unroll
        for (int mf = 0; mf < MF; ++mf)
#pragma unroll
            for (int nf = 0; nf < NF; ++nf)
#pragma unroll
                for (int r = 0; r < 4; ++r) {
                    int o = o0 + o0w + mf * 16 + (quad << 2) + r;
                    int p = p0 + p0w + nf * 16 + l16;
                    out[((size_t)b * O + o) * HW + p] = f2bf(fmaxf(acc[mf][nf][r], 0.f));
                }
    } else {
        float* pb = part + (size_t)chunk * 8 * O * HW;
#pragma unroll
        for (int mf = 0; mf < MF; ++mf)
#pragma unroll
            for (int nf = 0; nf < NF; ++nf)
#pragma unroll
                for (int r = 0; r < 4; ++r) {
                    int o = o0 + o0w + mf * 16 + (quad << 2) + r;
                    int p = p0 + p0w + nf * 16 + l16;
                    pb[((size_t)b * O + o) * HW + p] = acc[mf][nf][r];
                }
    }
}

// sum partial chunks + ReLU -> bf16 activation
__global__ void reduce_relu_kernel(const float* __restrict__ part,
                                   unsigned short* __restrict__ out,
                                   int per4, int nChunks)
{
    int idx = blockIdx.x * blockDim.x + threadIdx.x;
    if (idx >= per4) return;
    const float4* p4 = (const float4*)part;
    float4 s = p4[idx];
    for (int ch = 1; ch < nChunks; ++ch) {
        float4 v = p4[(size_t)ch * per4 + idx];
        s.x += v.x; s.y += v.y; s.z += v.z; s.w += v.w;
    }
    ushort4v r;
    r.x = f2bf(fmaxf(s.x, 0.f)); r.y = f2bf(fmaxf(s.y, 0.f));
    r.z = f2bf(fmaxf(s.z, 0.f)); r.w = f2bf(fmaxf(s.w, 0.f));
    ((ushort4v*)out)[idx] = r;
}

// sum partial chunks + ReLU + 2x2 maxpool -> bf16 activation
__global__ void reduce_relu_pool_kernel(const float* __restrict__ part,
                                        unsigned short* __restrict__ out,
                                        int H, int per, int nChunks, int total)
{
    int idx = blockIdx.x * blockDim.x + threadIdx.x;
    if (idx >= total) return;
    int H2 = H >> 1;
    int x2 = idx % H2;
    int t  = idx / H2;
    int y2 = t % H2;
    t /= H2;                       // t = b*C + c
    int base = (t * H + 2 * y2) * H + 2 * x2;
    float s0 = 0.f, s1 = 0.f, s2 = 0.f, s3 = 0.f;
    for (int ch = 0; ch < nChunks; ++ch) {
        const float* p = part + (size_t)ch * per + base;
        s0 += p[0]; s1 += p[1]; s2 += p[H]; s3 += p[H + 1];
    }
    out[idx] = f2bf(fmaxf(fmaxf(fmaxf(s0, s1), fmaxf(s2, s3)), 0.f));
}

// bf16 2x2 maxpool (post-ReLU values; conversions exact)
__global__ void maxpool_kernel(const unsigned short* __restrict__ in,
                               unsigned short* __restrict__ out,
                               int H, int W, int total)
{
    int idx = blockIdx.x * blockDim.x + threadIdx.x;
    if (idx >= total) return;
    int W2 = W >> 1, H2 = H >> 1;
    int x2 = idx % W2;
    int t  = idx / W2;
    int y2 = t % H2;
    t /= H2;
    const unsigned short* p = in + ((size_t)t * H + 2 * y2) * W + 2 * x2;
    float m = fmaxf(fmaxf(bf2f(p[0]), bf2f(p[1])), fmaxf(bf2f(p[W]), bf2f(p[W + 1])));
    out[idx] = f2bf(m);
}

// 4x4 avg pool, bf16 in -> fp32 out
__global__ void avgpool_kernel(const unsigned short* __restrict__ in,
                               float* __restrict__ out, int total)
{
    int idx = blockIdx.x * blockDim.x + threadIdx.x;
    if (idx >= total) return;
    const unsigned short* p = in + (size_t)idx * 16;
    float s = 0.f;
#pragma unroll
    for (int i = 0; i < 16; ++i) s += bf2f(p[i]);
    out[idx] = s * (1.0f / 16.0f);
}

__global__ __launch_bounds__(256) void fc_kernel(
    const float* __restrict__ x, const float* __restrict__ w,
    const float* __restrict__ bias, float* __restrict__ out,
    int K, int O, int relu)
{
    int o = blockIdx.x;
    float acc[8] = {0.f,0.f,0.f,0.f,0.f,0.f,0.f,0.f};
    const float* wr = w + (size_t)o * K;
    for (int k = threadIdx.x; k < K; k += 256) {
        float wv = wr[k];
#pragma unroll
        for (int b = 0; b < 8; ++b) acc[b] += wv * x[(size_t)b * K + k];
    }
    __shared__ float red[8][256];
#pragma unroll
    for (int b = 0; b < 8; ++b) red[b][threadIdx.x] = acc[b];
    __syncthreads();
    for (int s = 128; s > 0; s >>= 1) {
        if (threadIdx.x < s) {
#pragma unroll
            for (int b = 0; b < 8; ++b) red[b][threadIdx.x] += red[b][threadIdx.x + s];
        }
        __syncthreads();
    }
    if (threadIdx.x < 8) {
        float v = red[threadIdx.x][0] + bias[o];
        if (relu) v = fmaxf(v, 0.f);
        out[(size_t)threadIdx.x * O + o] = v;
    }
}

// ---------------------------------------------------------------------------
// Host orchestration (round-4 chunking: nCh = 1/2/2/4/16)
// ---------------------------------------------------------------------------
extern "C" void kernel_launch(void* const* d_in, const int* in_sizes, int n_in,
                              void* d_out, int out_size, void* d_ws, size_t ws_size,
                              hipStream_t stream) {
    const float* x    = (const float*)d_in[0];
    const float* wf[13];
    for (int i = 0; i < 13; ++i) wf[i] = (const float*)d_in[1 + i];
    const float* fc1w = (const float*)d_in[14];
    const float* fc1b = (const float*)d_in[15];
    const float* fc2w = (const float*)d_in[16];
    const float* fc2b = (const float*)d_in[17];
    const float* fc3w = (const float*)d_in[18];
    const float* fc3b = (const float*)d_in[19];
    float* out = (float*)d_out;

    char* ws = (char*)d_ws;
    auto alloc = [&](size_t bytes) -> char* {
        char* p = ws;
        ws += (bytes + 255) & ~(size_t)255;
        return p;
    };

    const int sizes[5] = {128, 64, 32, 16, 8};
    Tap* tabs[5];
    int* tabTs[5];
    for (int i = 0; i < 5; ++i) {
        int HW = sizes[i] * sizes[i];
        tabs[i]  = (Tap*)alloc((size_t)HW * 9 * sizeof(Tap));
        tabTs[i] = (int*)alloc((size_t)HW * 9 * 8 * sizeof(int));
    }
    unsigned short* actA = (unsigned short*)alloc((size_t)8 * 64 * 128 * 128 * 2);
    unsigned short* actB = (unsigned short*)alloc((size_t)8 * 64 * 128 * 128 * 2);
    float* partial = (float*)alloc((size_t)2 * 8 * 128 * 4096 * sizeof(float)); // 33.6 MB max
    const int Cs[13] = {3, 64, 64, 128, 128, 256, 256, 256, 512, 512, 512, 512, 512};
    const int Os[13] = {64, 64, 128, 128, 256, 256, 256, 512, 512, 512, 512, 512, 512};
    unsigned short* wPk[13];
    wPk[0] = nullptr;
    for (int i = 1; i < 13; ++i)
        wPk[i] = (unsigned short*)alloc((size_t)Os[i] * Cs[i] * 9 * sizeof(unsigned short));
    float* pooled = (float*)alloc((size_t)8 * 512 * sizeof(float));
    float* fcb1 = (float*)alloc((size_t)8 * 4096 * sizeof(float));
    float* fcb2 = (float*)alloc((size_t)8 * 4096 * sizeof(float));

    for (int i = 0; i < 5; ++i) {
        int total = sizes[i] * sizes[i] * 9;
        build_table_kernel<<<(total + 255) / 256, 256, 0, stream>>>(tabs[i], tabTs[i], sizes[i]);
    }
    for (int i = 1; i < 13; ++i) {
        int total = Os[i] * Cs[i] * 9;
        pack_w_kernel<<<(total + 255) / 256, 256, 0, stream>>>(wf[i], wPk[i], Os[i], Cs[i], total);
    }

    auto convM = [&](const unsigned short* in, const unsigned short* wp, int* tabT,
                     unsigned short* o, int C, int O, int S, int nCh, bool leavePartial) {
        int HW = S * S;
        int Cchunk = C / nCh;
        if (O == 64) {
            dim3 grid(HW / 64, 1, 8 * nCh);
            dconv_mfma<64><<<grid, 256, 0, stream>>>(in, wp, tabT, o, partial, C, O, HW, Cchunk, nCh);
        } else {
            dim3 grid(HW / 64, O / 128, 8 * nCh);
            dconv_mfma<128><<<grid, 256, 0, stream>>>(in, wp, tabT, o, partial, C, O, HW, Cchunk, nCh);
        }
        if (nCh > 1 && !leavePartial) {
            int per4 = 8 * O * HW / 4;
            reduce_relu_kernel<<<(per4 + 255) / 256, 256, 0, stream>>>(partial, o, per4, nCh);
        }
    };
    auto fusedPool = [&](unsigned short* o, int C, int H, int nCh) {
        int per = 8 * C * H * H;
        int total = per / 4;
        reduce_relu_pool_kernel<<<(total + 255) / 256, 256, 0, stream>>>(partial, o, H, per, nCh, total);
    };

    // conv1_1: fp32 input path (C=3) -> bf16 actA
    {
        dim3 grid(128 * 128 / 64, 1, 8);
        dconv_f32_kernel<<<grid, 256, 0, stream>>>(x, wf[0], tabs[0], actA, 3, 64, 128 * 128);
    }
    convM(actA, wPk[1],  tabTs[0], actB, 64,  64,  128, 1, false);   // conv1_2 -> actB
    {
        int total = 8 * 64 * 64 * 64;
        maxpool_kernel<<<(total + 255) / 256, 256, 0, stream>>>(actB, actA, 128, 128, total);
    }
    convM(actA, wPk[2],  tabTs[1], actB, 64,  128, 64, 2, false);    // conv2_1 -> actB
    convM(actB, wPk[3],  tabTs[1], nullptr, 128, 128, 64, 2, true);  // conv2_2 -> partial
    fusedPool(actA, 128, 64, 2);                                     // -> actA (128ch @32^2)
    convM(actA, wPk[4],  tabTs[2], actB, 128, 256, 32, 2, false);    // conv3_1 -> actB
    convM(actB, wPk[5],  tabTs[2], actA, 256, 256, 32, 2, false);    // conv3_2 -> actA
    convM(actA, wPk[6],  tabTs[2], nullptr, 256, 256, 32, 2, true);  // conv3_3 -> partial
    fusedPool(actB, 256, 32, 2);                                     // -> actB (256ch @16^2)
    convM(actB, wPk[7],  tabTs[3], actA, 256, 512, 16, 4, false);    // conv4_1 -> actA
    convM(actA, wPk[8],  tabTs[3], actB, 512, 512, 16, 4, false);    // conv4_2 -> actB
    convM(actB, wPk[9],  tabTs[3], nullptr, 512, 512, 16, 4, true);  // conv4_3 -> partial
    fusedPool(actA, 512, 16, 4);                                     // -> actA (512ch @8^2)
    convM(actA, wPk[10], tabTs[4], actB, 512, 512, 8, 16, false);    // conv5_1 -> actB
    convM(actB, wPk[11], tabTs[4], actA, 512, 512, 8, 16, false);    // conv5_2 -> actA
    convM(actA, wPk[12], tabTs[4], nullptr, 512, 512, 8, 16, true);  // conv5_3 -> partial
    fusedPool(actB, 512, 8, 16);                                     // -> actB (512ch @4^2)

    avgpool_kernel<<<(4096 + 255) / 256, 256, 0, stream>>>(actB, pooled, 8 * 512);

    fc_kernel<<<4096, 256, 0, stream>>>(pooled, fc1w, fc1b, fcb1, 512,  4096, 1);
    fc_kernel<<<4096, 256, 0, stream>>>(fcb1,   fc2w, fc2b, fcb2, 4096, 4096, 1);
    fc_kernel<<<30,   256, 0, stream>>>(fcb2,   fc3w, fc3b, out,  4096, 30,   0);
}